// Round 4
// baseline (1641.865 us; speedup 1.0000x reference)
//
#include <hip/hip_runtime.h>
#include <math.h>

#define TT 512
#define NN 256
#define HH 512
constexpr float AL = 0.1f;

typedef unsigned int uint;
typedef uint u32x16 __attribute__((ext_vector_type(16)));
using half2v = decltype(__builtin_amdgcn_cvt_pkrtz(0.0f, 0.0f));

struct Args {
  const float* initdir; const float* vel; const float* fc_w; const float* fc_b;
  const float* W_in; const float* W_rec; const float* W_out; const float* bias;
  float* out; uint* actbuf; unsigned* ctrs;
};

__global__ void init_ctrs(unsigned* ctrs) {
  ctrs[threadIdx.x + blockIdx.x * blockDim.x] = 0u;  // 8192 u32 = 32KB
}

__device__ __forceinline__ void st_agent_u32(uint* p, uint v) {
  __hip_atomic_store(p, v, __ATOMIC_RELAXED, __HIP_MEMORY_SCOPE_AGENT);
}
__device__ __forceinline__ uint ld_agent_u32(const uint* p) {
  return __hip_atomic_load(p, __ATOMIC_RELAXED, __HIP_MEMORY_SCOPE_AGENT);
}
__device__ __forceinline__ unsigned ld_ctr(const unsigned* p) {
  return __hip_atomic_load(p, __ATOMIC_RELAXED, __HIP_MEMORY_SCOPE_AGENT);
}
__device__ __forceinline__ float dot2f(uint w, uint a, float c) {
#if __has_builtin(__builtin_amdgcn_fdot2)
  return __builtin_amdgcn_fdot2(__builtin_bit_cast(half2v, w),
                                __builtin_bit_cast(half2v, a), c, false);
#else
  half2v wv = __builtin_bit_cast(half2v, w);
  half2v av = __builtin_bit_cast(half2v, a);
  c = fmaf((float)wv.x, (float)av.x, c);
  c = fmaf((float)wv.y, (float)av.y, c);
  return c;
#endif
}

// 256 WGs x 512 threads, cooperative. Cluster = 2 WGs sharing 2 batch rows.
// WG rank c owns cols [256c, 256c+256). Weights: f16-packed pairs in VGPRs
// (asm-pinned). Waves 0-3 (g=0) always GEMV the LOCAL slice (no wait);
// waves 4-7 (g=1) poll the peer, load its packed acts, GEMV the foreign
// slice. Two __syncthreads per step total.
__global__ __launch_bounds__(512, 2)
void rnn_kernel(Args a) {
  __shared__ alignas(16) uint act_pk[512];   // [pair][n] packed f16, 2KB
  __shared__ float red[2][2][256];           // [g][n][j], 4KB

  const int tid = threadIdx.x;
  const int wav = tid >> 6;
  const int lan = tid & 63;
  const int bid = blockIdx.x;
  const int xcd = bid & 7, k = bid >> 3;
  const int c = k & 1;                  // cluster rank (slice index)
  const int grp = xcd * 16 + (k >> 1);  // n-group 0..127 (2 rows each)

  const int g = tid >> 8;               // 0 = local waves, 1 = foreign waves
  const int j = tid & 255;
  const int uj = c * 256 + j;           // this thread's column (GEMV + update)
  const int n = g;                      // phase-B row alias
  const int ugn = grp * 2 + n;          // global batch row (phase B)

  const int gpbase = (g == 0) ? (c * 128) : ((1 - c) * 128);  // my pair base
  const int fpbase = (1 - c) * 128;                           // foreign pairs

  // ---- W_rec slice -> f16-packed pairs in registers, asm-pinned
  u32x16 W[8];
  {
    const float* wr = a.W_rec + (size_t)(2 * gpbase) * HH + uj;
#pragma unroll
    for (int p = 0; p < 128; ++p) {
      float w0 = wr[(2 * p) * HH];
      float w1 = wr[(2 * p + 1) * HH];
      W[p >> 4][p & 15] = __builtin_bit_cast(uint, __builtin_amdgcn_cvt_pkrtz(w0, w1));
    }
  }
  asm volatile("" : "+v"(W[0]), "+v"(W[1]), "+v"(W[2]), "+v"(W[3]),
                    "+v"(W[4]), "+v"(W[5]), "+v"(W[6]), "+v"(W[7]));

  // ---- W_out rows for the out-projection wave (wave 4), f32 exact
  float wo[16];
  if (wav == 4) {
#pragma unroll
    for (int r = 0; r < 8; ++r) {
      wo[r * 2]     = a.W_out[(8 * lan + r) * 2 + 0];
      wo[r * 2 + 1] = a.W_out[(8 * lan + r) * 2 + 1];
    }
  }

  // per-thread parameters
  const float fw0 = a.fc_w[uj * 2], fw1 = a.fc_w[uj * 2 + 1], fb = a.fc_b[uj];
  const float wi0 = AL * a.W_in[uj], wi1 = AL * a.W_in[HH + uj];
  const float bj = AL * a.bias[uj];
  const float id0 = a.initdir[ugn * 2], id1 = a.initdir[ugn * 2 + 1];

  float h = fmaf(id0, fw0, fmaf(id1, fw1, fb));  // h0

  uint* buf0 = a.actbuf + (size_t)grp * 512;           // parity 0, [pair][n]
  uint* buf1 = a.actbuf + (size_t)(128 + grp) * 512;   // parity 1
  unsigned* myctr   = a.ctrs + bid * 32;               // 128B stride
  unsigned* peerctr = a.ctrs + (bid ^ 8) * 32;

  const float2* velp = (const float2*)a.vel;
  float2* outp = (float2*)a.out;

  // phase-B act emit: pack f16 pair, write LDS (own slice) + global (peer),
  // per-wave drain + bump, then one barrier for LDS visibility.
  auto emit_act = [&](uint* bufw, float act) {
    float aR = __shfl_xor(act, 1);
    if ((j & 1) == 0) {
      uint pk = __builtin_bit_cast(uint, __builtin_amdgcn_cvt_pkrtz(act, aR));
      int uidx = uj + n;  // == (uj>>1)*2 + n, uj even
      act_pk[uidx] = pk;
      st_agent_u32(bufw + uidx, pk);
    }
    asm volatile("" ::: "memory");
    __builtin_amdgcn_s_waitcnt(0);      // this wave's stores at coherence pt
    asm volatile("" ::: "memory");
    if (lan == 0)
      __hip_atomic_fetch_add(myctr, 1u, __ATOMIC_RELAXED, __HIP_MEMORY_SCOPE_AGENT);
    __syncthreads();                    // B2: own-slice LDS visible to all
  };

  emit_act(buf0, fmaxf(tanhf(h), 0.0f));  // act for step 0 -> parity 0

  for (int t = 0; t <= TT; ++t) {
    float2 xv = make_float2(0.f, 0.f);
    if (t < TT) xv = velp[t * NN + ugn];  // issued early, used in phase B

    if (g == 1) {
      // ---- exchange: wait for peer's 8 wave-bumps, pull foreign slice
      const uint* bufr = (t & 1) ? buf1 : buf0;
      unsigned tgt = 8u * (unsigned)(t + 1);
      while (ld_ctr(peerctr) < tgt) {}
      asm volatile("" ::: "memory");
      int base = fpbase * 2 + 4 * lan;
      uint v0 = ld_agent_u32(bufr + base + 0);
      uint v1 = ld_agent_u32(bufr + base + 1);
      uint v2 = ld_agent_u32(bufr + base + 2);
      uint v3 = ld_agent_u32(bufr + base + 3);
      *(uint4*)&act_pk[base] = make_uint4(v0, v1, v2, v3);

      // ---- out[t-1] = act_t @ W_out (row grp*2+c), wave 4 only
      if (wav == 4 && t > 0) {
        float q0 = 0.f, q1 = 0.f;
#pragma unroll
        for (int r = 0; r < 2; ++r) {
          uint4 av = *(const uint4*)&act_pk[8 * lan + 4 * r];
          uint u0 = (c == 0) ? av.x : av.y;   // (pair, n=c)
          uint u1 = (c == 0) ? av.z : av.w;   // (pair+1, n=c)
          half2v a0 = __builtin_bit_cast(half2v, u0);
          half2v a1 = __builtin_bit_cast(half2v, u1);
          float f0 = (float)a0.x, f1 = (float)a0.y;
          float f2 = (float)a1.x, f3 = (float)a1.y;
          q0 = fmaf(f0, wo[(4 * r + 0) * 2], q0); q1 = fmaf(f0, wo[(4 * r + 0) * 2 + 1], q1);
          q0 = fmaf(f1, wo[(4 * r + 1) * 2], q0); q1 = fmaf(f1, wo[(4 * r + 1) * 2 + 1], q1);
          q0 = fmaf(f2, wo[(4 * r + 2) * 2], q0); q1 = fmaf(f2, wo[(4 * r + 2) * 2 + 1], q1);
          q0 = fmaf(f3, wo[(4 * r + 3) * 2], q0); q1 = fmaf(f3, wo[(4 * r + 3) * 2 + 1], q1);
        }
#pragma unroll
        for (int off = 32; off; off >>= 1) {
          q0 += __shfl_down(q0, off);
          q1 += __shfl_down(q1, off);
        }
        if (lan == 0) outp[(t - 1) * NN + (grp * 2 + c)] = make_float2(q0, q1);
      }
    }
    if (t == TT) break;

    // ---- GEMV over my 128 pairs (local waves start immediately)
    float acc0 = 0.f, acc1 = 0.f, acc2 = 0.f, acc3 = 0.f;
#pragma unroll
    for (int kk = 0; kk < 64; kk += 2) {
      uint4 av0 = *(const uint4*)&act_pk[(gpbase + 2 * kk) * 2];
      uint4 av1 = *(const uint4*)&act_pk[(gpbase + 2 * kk + 2) * 2];
      acc0 = dot2f(W[(2 * kk) >> 4][(2 * kk) & 15], av0.x, acc0);
      acc1 = dot2f(W[(2 * kk) >> 4][(2 * kk) & 15], av0.y, acc1);
      acc2 = dot2f(W[(2 * kk + 1) >> 4][(2 * kk + 1) & 15], av0.z, acc2);
      acc3 = dot2f(W[(2 * kk + 1) >> 4][(2 * kk + 1) & 15], av0.w, acc3);
      acc0 = dot2f(W[(2 * kk + 2) >> 4][(2 * kk + 2) & 15], av1.x, acc0);
      acc1 = dot2f(W[(2 * kk + 2) >> 4][(2 * kk + 2) & 15], av1.y, acc1);
      acc2 = dot2f(W[(2 * kk + 3) >> 4][(2 * kk + 3) & 15], av1.z, acc2);
      acc3 = dot2f(W[(2 * kk + 3) >> 4][(2 * kk + 3) & 15], av1.w, acc3);
    }
    red[g][0][j] = acc0 + acc2;  // partial y for (col uj, n=0)
    red[g][1][j] = acc1 + acc3;  // partial y for (col uj, n=1)
    __syncthreads();             // B1

    // ---- phase B: 2-way reduce + leaky update (thread owns (n, uj))
    float y = red[0][n][j] + red[1][n][j];
    h = fmaf(0.9f, h, fmaf(AL, y, fmaf(xv.x, wi0, fmaf(xv.y, wi1, bj))));
    uint* bufw = (t & 1) ? buf0 : buf1;  // act_{t+1} -> parity (t+1)&1
    emit_act(bufw, fmaxf(tanhf(h), 0.0f));
  }
}

extern "C" void kernel_launch(void* const* d_in, const int* in_sizes, int n_in,
                              void* d_out, int out_size, void* d_ws, size_t ws_size,
                              hipStream_t stream) {
  (void)in_sizes; (void)n_in; (void)out_size; (void)ws_size;
  Args a;
  a.initdir = (const float*)d_in[0];
  a.vel     = (const float*)d_in[1];
  a.fc_w    = (const float*)d_in[2];
  a.fc_b    = (const float*)d_in[3];
  a.W_in    = (const float*)d_in[4];
  a.W_rec   = (const float*)d_in[5];
  a.W_out   = (const float*)d_in[6];
  a.bias    = (const float*)d_in[7];
  a.out     = (float*)d_out;
  a.actbuf  = (uint*)d_ws;                                  // 2*128*512 u32 = 512KB
  a.ctrs    = (unsigned*)((char*)d_ws + 512 * 1024);        // +32KB counters

  init_ctrs<<<8, 1024, 0, stream>>>(a.ctrs);

  void* args[] = { &a };
  hipLaunchCooperativeKernel((const void*)rnn_kernel, dim3(256), dim3(512),
                             args, 0, stream);
}

// Round 6
// 1557.854 us; speedup vs baseline: 1.0539x; 1.0539x over previous
//
#include <hip/hip_runtime.h>
#include <math.h>

#define TT 512
#define NN 256
#define HH 512
constexpr float AL = 0.1f;

typedef unsigned int uint;
typedef unsigned long long u64;
typedef uint u32x16 __attribute__((ext_vector_type(16)));
using half2v = decltype(__builtin_amdgcn_cvt_pkrtz(0.0f, 0.0f));

struct Args {
  const float* initdir; const float* vel; const float* fc_w; const float* fc_b;
  const float* W_in; const float* W_rec; const float* W_out; const float* bias;
  float* out; u64* actbuf;
};

// Zero all tags each launch: graph replays must not see stale tags
// (tag T from replay k would alias want=T in replay k+1 -> stale-data race).
__global__ void zero_actbuf(u64* p) {
  p[blockIdx.x * 512 + threadIdx.x] = 0ull;  // 256*512 = 131072 u64 = 1MB
}

__device__ __forceinline__ float dot2f(uint w, uint a, float c) {
#if __has_builtin(__builtin_amdgcn_fdot2)
  return __builtin_amdgcn_fdot2(__builtin_bit_cast(half2v, w),
                                __builtin_bit_cast(half2v, a), c, false);
#else
  half2v wv = __builtin_bit_cast(half2v, w);
  half2v av = __builtin_bit_cast(half2v, a);
  c = fmaf((float)wv.x, (float)av.x, c);
  c = fmaf((float)wv.y, (float)av.y, c);
  return c;
#endif
}

// 256 WGs x 512 threads, cooperative. Cluster = 2 WGs (bid, bid^8) sharing 2
// batch rows; WG rank c owns cols [256c,256c+256). Exchange = tagged u64
// (packed f16 acts | tag<<32) via agent-scope relaxed atomics (proven path,
// rounds 2-4): producer fire-and-forgets one 8B store; consumer polls the
// data word itself. No counter RMW, no producer drain, no placement
// assumptions. launch_bounds(512,1): grid is 1 WG/CU anyway; 256-reg budget
// makes the 128 weight dwords true VGPRs (kills the AGPR shuttle seen in r4).
__global__ __launch_bounds__(512, 1)
void rnn_kernel(Args a) {
  __shared__ alignas(16) uint act_pk[512];  // [2*pair + n] packed f16, 2KB
  __shared__ float red[2][2][256];          // [g][n][j] partials, 4KB

  const int tid = threadIdx.x;
  const int wav = tid >> 6, lan = tid & 63;
  const int bid = blockIdx.x;
  const int xcd = bid & 7, kk = bid >> 3;
  const int c = kk & 1;                  // cluster rank (col-slice index)
  const int grp = xcd * 16 + (kk >> 1);  // n-group 0..127 (2 rows each)
  const int g = tid >> 8;                // 0 = local waves, 1 = foreign waves
  const int j = tid & 255;
  const int uj = c * 256 + j;            // this thread's column
  const int n = g;                       // phase-B batch-row alias
  const int ugn = grp * 2 + n;
  const int gp_pb = (g == 0) ? (c * 128) : ((1 - c) * 128);  // GEMV pair base

  // ---- W_rec slice -> f16-packed pairs in registers (pinned)
  u32x16 W[8];
  {
    const float* wr = a.W_rec + (size_t)(2 * gp_pb) * HH + uj;
#pragma unroll
    for (int p = 0; p < 128; ++p) {
      float w0 = wr[(2 * p) * HH];
      float w1 = wr[(2 * p + 1) * HH];
      W[p >> 4][p & 15] =
          __builtin_bit_cast(uint, __builtin_amdgcn_cvt_pkrtz(w0, w1));
    }
  }
  asm volatile("" : "+v"(W[0]), "+v"(W[1]), "+v"(W[2]), "+v"(W[3]),
                    "+v"(W[4]), "+v"(W[5]), "+v"(W[6]), "+v"(W[7]));

  float wo[16];  // W_out rows for out-projection (wave 0 only), f32 exact
  if (wav == 0) {
#pragma unroll
    for (int r = 0; r < 8; ++r) {
      wo[r * 2]     = a.W_out[(8 * lan + r) * 2 + 0];
      wo[r * 2 + 1] = a.W_out[(8 * lan + r) * 2 + 1];
    }
  }

  const float fw0 = a.fc_w[uj * 2], fw1 = a.fc_w[uj * 2 + 1], fb = a.fc_b[uj];
  const float wi0 = AL * a.W_in[uj], wi1 = AL * a.W_in[HH + uj];
  const float bj = AL * a.bias[uj];
  const float id0 = a.initdir[ugn * 2], id1 = a.initdir[ugn * 2 + 1];

  float h = fmaf(id0, fw0, fmaf(id1, fw1, fb));  // h0

  u64* buf0 = a.actbuf + (size_t)grp * 512;          // parity 0
  u64* buf1 = a.actbuf + (size_t)(128 + grp) * 512;  // parity 1
  const float2* velp = (const float2*)a.vel;
  float2* outp = (float2*)a.out;

  // emit act: own half -> LDS directly; tagged u64 -> cluster buffer (LLC).
  // One fire-and-forget 8B store; the tag travels with the data.
  auto emit = [&](u64* bufw, float act, uint tag) {
    float aR = __shfl_xor(act, 1);
    if ((j & 1) == 0) {
      uint pk = __builtin_bit_cast(uint, __builtin_amdgcn_cvt_pkrtz(act, aR));
      int idx = c * 256 + j + n;  // = 2*pair + n
      act_pk[idx] = pk;
      u64 v = (u64)pk | ((u64)tag << 32);
      __hip_atomic_store(bufw + idx, v, __ATOMIC_RELAXED,
                         __HIP_MEMORY_SCOPE_AGENT);
    }
  };

  auto gemv = [&](int rg) {
    float acc0 = 0.f, acc1 = 0.f, acc2 = 0.f, acc3 = 0.f;
#pragma unroll
    for (int q = 0; q < 32; ++q) {
      uint4 av0 = *(const uint4*)&act_pk[(gp_pb + 4 * q) * 2];  // broadcast
      uint4 av1 = *(const uint4*)&act_pk[(gp_pb + 4 * q + 2) * 2];
      acc0 = dot2f(W[(4*q+0) >> 4][(4*q+0) & 15], av0.x, acc0);
      acc1 = dot2f(W[(4*q+0) >> 4][(4*q+0) & 15], av0.y, acc1);
      acc2 = dot2f(W[(4*q+1) >> 4][(4*q+1) & 15], av0.z, acc2);
      acc3 = dot2f(W[(4*q+1) >> 4][(4*q+1) & 15], av0.w, acc3);
      acc0 = dot2f(W[(4*q+2) >> 4][(4*q+2) & 15], av1.x, acc0);
      acc1 = dot2f(W[(4*q+2) >> 4][(4*q+2) & 15], av1.y, acc1);
      acc2 = dot2f(W[(4*q+3) >> 4][(4*q+3) & 15], av1.z, acc2);
      acc3 = dot2f(W[(4*q+3) >> 4][(4*q+3) & 15], av1.w, acc3);
    }
    red[rg][0][j] = acc0 + acc2;
    red[rg][1][j] = acc1 + acc3;
  };

  emit(buf0, fmaxf(tanhf(h), 0.0f), 1u);  // act_0, tag 1, parity 0
  __syncthreads();

  for (int t = 0; t <= TT; ++t) {
    float2 xv = make_float2(0.f, 0.f);
    if (t < TT) xv = velp[t * NN + ugn];

    // ---- stage 1: g=1 polls foreign tagged acts; g=0 GEMVs local slice
    if (g == 1) {
      const u64* bufr = (t & 1) ? buf1 : buf0;
      const uint want = (uint)(t + 1);
      const int idx = (1 - c) * 256 + j;
      u64 v;
      do {
        v = __hip_atomic_load(bufr + idx, __ATOMIC_RELAXED,
                              __HIP_MEMORY_SCOPE_AGENT);
      } while ((uint)(v >> 32) != want);
      act_pk[idx] = (uint)v;
    } else if (t < TT) {
      gemv(0);
    }
    __syncthreads();  // B1: foreign acts in LDS; red[0] done

    // ---- stage 3: g=1 GEMVs foreign; wave 0 does out[t-1] under it
    if (g == 1) {
      if (t < TT) gemv(1);
    } else if (wav == 0 && t > 0) {
      float q0 = 0.f, q1 = 0.f;
#pragma unroll
      for (int r = 0; r < 2; ++r) {
        uint4 av = *(const uint4*)&act_pk[8 * lan + 4 * r];
        uint u0 = c ? av.y : av.x;   // (pair 4*lan+2r,   n=c)
        uint u1 = c ? av.w : av.z;   // (pair 4*lan+2r+1, n=c)
        half2v a0 = __builtin_bit_cast(half2v, u0);
        half2v a1 = __builtin_bit_cast(half2v, u1);
        float f0 = (float)a0.x, f1 = (float)a0.y;
        float f2 = (float)a1.x, f3 = (float)a1.y;
        q0 = fmaf(f0, wo[(4*r+0)*2], q0); q1 = fmaf(f0, wo[(4*r+0)*2+1], q1);
        q0 = fmaf(f1, wo[(4*r+1)*2], q0); q1 = fmaf(f1, wo[(4*r+1)*2+1], q1);
        q0 = fmaf(f2, wo[(4*r+2)*2], q0); q1 = fmaf(f2, wo[(4*r+2)*2+1], q1);
        q0 = fmaf(f3, wo[(4*r+3)*2], q0); q1 = fmaf(f3, wo[(4*r+3)*2+1], q1);
      }
#pragma unroll
      for (int off = 32; off; off >>= 1) {
        q0 += __shfl_down(q0, off);
        q1 += __shfl_down(q1, off);
      }
      if (lan == 0) outp[(t - 1) * NN + (grp * 2 + c)] = make_float2(q0, q1);
    }
    if (t == TT) break;
    __syncthreads();  // B2: red[1] done; act_pk out-proj reads done

    // ---- stage 5: leaky update + emit act_{t+1}
    float y = red[0][n][j] + red[1][n][j];
    h = fmaf(0.9f, h, fmaf(AL, y, fmaf(xv.x, wi0, fmaf(xv.y, wi1, bj))));
    u64* bufw = (t & 1) ? buf0 : buf1;  // parity (t+1)&1
    emit(bufw, fmaxf(tanhf(h), 0.0f), (uint)(t + 2));
    __syncthreads();  // B3: own half in LDS for next stage-1 GEMV
  }
}

extern "C" void kernel_launch(void* const* d_in, const int* in_sizes, int n_in,
                              void* d_out, int out_size, void* d_ws, size_t ws_size,
                              hipStream_t stream) {
  (void)in_sizes; (void)n_in; (void)out_size; (void)ws_size;
  Args a;
  a.initdir = (const float*)d_in[0];
  a.vel     = (const float*)d_in[1];
  a.fc_w    = (const float*)d_in[2];
  a.fc_b    = (const float*)d_in[3];
  a.W_in    = (const float*)d_in[4];
  a.W_rec   = (const float*)d_in[5];
  a.W_out   = (const float*)d_in[6];
  a.bias    = (const float*)d_in[7];
  a.out     = (float*)d_out;
  a.actbuf  = (u64*)d_ws;  // 2*128*512 u64 = 1MB

  zero_actbuf<<<256, 512, 0, stream>>>(a.actbuf);

  void* args[] = { &a };
  hipLaunchCooperativeKernel((const void*)rnn_kernel, dim3(256), dim3(512),
                             args, 0, stream);
}

// Round 7
// 1231.761 us; speedup vs baseline: 1.3329x; 1.2647x over previous
//
#include <hip/hip_runtime.h>
#include <math.h>

#define TT 512
#define NN 256
#define HH 512
constexpr float AL = 0.1f;

typedef unsigned int uint;
typedef unsigned long long u64;
typedef uint u32x16 __attribute__((ext_vector_type(16)));
using half2v = decltype(__builtin_amdgcn_cvt_pkrtz(0.0f, 0.0f));

struct Args {
  const float* initdir; const float* vel; const float* fc_w; const float* fc_b;
  const float* W_in; const float* W_rec; const float* W_out; const float* bias;
  float* out; u64* pbuf;
};

// Replay-safe prologues: tags must start at 0 (poll wants 1..512), and out
// is accumulated via atomicAdd so it must be zeroed every launch.
__global__ void zero_pbuf(u64* p) { p[blockIdx.x * 512 + threadIdx.x] = 0ull; }   // 256x512 u64 = 1MB
__global__ void zero_out(float4* p) { p[blockIdx.x * 512 + threadIdx.x] = float4{0,0,0,0}; } // 128x512 f4

// Force-VGPR dot2: "v" constraints at every use make AGPR residency cost a
// copy per use, so the allocator assigns arch VGPRs (budget 256 at 1 WG/CU).
__device__ __forceinline__ void dot2asm(float& c, uint w, uint a) {
  asm("v_dot2_f32_f16 %0, %1, %2, %0" : "+v"(c) : "v"(w), "v"(a));
}

// 256 WGs x 512 threads, cooperative. Cluster = 2 WGs (bid, bid^8) sharing 2
// batch rows; WG c owns h-cols [256c, 256c+256). Each WG GEMVs ALL 512 cols
// over its OWN 256 acts (acts never exchanged); foreign-col partials ship as
// tagged u64 (f32 row0 | f16 row1 | tag16); own-col partials go through LDS.
// Both GEMVs run in parallel -> exchange latency is one ship+poll, not
// ship+poll+serial-foreign-GEMV. Out-projection: per-WG partial + atomicAdd.
__global__ __launch_bounds__(512, 1)
void rnn_kernel(Args a) {
  __shared__ alignas(16) uint actI[256];  // [2*ipair + row] packed f16, 1KB
  __shared__ float pred[2][256];          // own-col partials [row][jj], 2KB

  const int tid = threadIdx.x;
  const int lan = tid & 63;
  const int bid = blockIdx.x;
  const int kk = bid >> 3;
  const int c = kk & 1;                         // cluster rank (col slice)
  const int grp = (bid & 7) * 16 + (kk >> 1);   // n-group 0..127 (2 rows)
  const int own0 = c * 256;

  // GEMV identity: thread computes col j for BOTH rows over own 256 i's
  const int j = tid;
  const bool jown = (j >> 8) == c;
  const int jj_s = j & 255;  // slot within slice

  // update identity: thread owns h(row g, col own0+jj)
  const int g = tid >> 8;
  const int jj = tid & 255;
  const int ucol = own0 + jj;
  const int ugn = grp * 2 + g;

  // ---- W_rec: col j, own i-rows, as 128 packed-f16 pairs
  u32x16 W[8];
  {
    const float* wr = a.W_rec + (size_t)own0 * HH + j;
#pragma unroll
    for (int p = 0; p < 128; ++p) {
      float w0 = wr[(2 * p) * HH];
      float w1 = wr[(2 * p + 1) * HH];
      W[p >> 4][p & 15] =
          __builtin_bit_cast(uint, __builtin_amdgcn_cvt_pkrtz(w0, w1));
    }
  }

  // update-phase parameters
  const float fw0 = a.fc_w[ucol * 2], fw1 = a.fc_w[ucol * 2 + 1], fb = a.fc_b[ucol];
  const float wi0 = AL * a.W_in[ucol], wi1 = AL * a.W_in[HH + ucol];
  const float bj = AL * a.bias[ucol];
  const float wo0 = a.W_out[ucol * 2], wo1 = a.W_out[ucol * 2 + 1];
  const float id0 = a.initdir[ugn * 2], id1 = a.initdir[ugn * 2 + 1];

  float h = fmaf(id0, fw0, fmaf(id1, fw1, fb));  // h0

  u64* shipbase = a.pbuf + ((size_t)(bid ^ 8) * 2) * 256 + jj_s;  // + par*256
  const u64* pollbase = a.pbuf + ((size_t)bid * 2) * 256 + jj;    // + par*256
  const float2* velp = (const float2*)a.vel;
  float* outf = a.out;

  // act emit: pack (jj, jj^1) f16 pair into actI[(jj&~1) + g]
  auto emit = [&](float act) {
    float aR = __shfl_xor(act, 1);
    if (!(jj & 1))
      actI[jj + g] = __builtin_bit_cast(uint, __builtin_amdgcn_cvt_pkrtz(act, aR));
  };

  emit(fmaxf(tanhf(h), 0.0f));  // act_0 (own cols only; never exchanged)
  __syncthreads();

  for (int t = 0; t < TT; ++t) {
    const float2 xv = velp[t * NN + ugn];  // 2 addrs/WG, L2-resident
    const int par = t & 1;

    // ---- GEMV: col j, both rows, own 256 acts (wave-uniform broadcasts)
    float a00 = 0.f, a10 = 0.f, a01 = 0.f, a11 = 0.f;
#pragma unroll
    for (int q = 0; q < 64; ++q) {
      uint4 av = *(const uint4*)&actI[4 * q];  // (2q,r0)(2q,r1)(2q+1,r0)(2q+1,r1)
      dot2asm(a00, W[(2 * q) >> 4][(2 * q) & 15], av.x);
      dot2asm(a10, W[(2 * q) >> 4][(2 * q) & 15], av.y);
      dot2asm(a01, W[(2 * q + 1) >> 4][(2 * q + 1) & 15], av.z);
      dot2asm(a11, W[(2 * q + 1) >> 4][(2 * q + 1) & 15], av.w);
    }
    const float p0 = a00 + a01, p1 = a10 + a11;

    if (jown) {
      pred[0][jj_s] = p0;
      pred[1][jj_s] = p1;
    } else {
      // ship: f32 row0 | f16 row1 | tag16, one fire-and-forget 8B store
      uint p1h = __builtin_bit_cast(uint, __builtin_amdgcn_cvt_pkrtz(p1, 0.f)) & 0xffffu;
      u64 v = ((u64)__builtin_bit_cast(uint, p0) << 32) | ((u64)p1h << 16) |
              (u64)(uint)(t + 1);
      __hip_atomic_store(shipbase + par * 256, v, __ATOMIC_RELAXED,
                         __HIP_MEMORY_SCOPE_AGENT);
    }
    __syncthreads();  // B1: pred visible; ship already in flight

    // ---- poll foreign partial for (g, ucol), then leaky update
    u64 v;
    const u64* slot = pollbase + par * 256;
    do {
      v = __hip_atomic_load(slot, __ATOMIC_RELAXED, __HIP_MEMORY_SCOPE_AGENT);
    } while ((uint)(v & 0xffffu) != (uint)(t + 1));
    float pf;
    if (g == 0) {
      pf = __builtin_bit_cast(float, (uint)(v >> 32));
    } else {
      unsigned short hb = (unsigned short)((v >> 16) & 0xffffu);
      pf = (float)__builtin_bit_cast(_Float16, hb);
    }

    const float y = pred[g][jj] + pf;
    h = fmaf(0.9f, h, fmaf(AL, y, fmaf(xv.x, wi0, fmaf(xv.y, wi1, bj))));
    const float act = fmaxf(tanhf(h), 0.0f);

    // ---- out[t][ugn][:] partial: wave-reduce act*wo, 2 atomicAdds per wave
    float q0 = act * wo0, q1 = act * wo1;
#pragma unroll
    for (int off = 32; off; off >>= 1) {
      q0 += __shfl_down(q0, off);
      q1 += __shfl_down(q1, off);
    }
    if (lan == 0) {
      atomicAdd(&outf[(t * NN + ugn) * 2 + 0], q0);
      atomicAdd(&outf[(t * NN + ugn) * 2 + 1], q1);
    }

    emit(act);        // act_{t+1} -> LDS (own cols only)
    __syncthreads();  // B2: actI ready for next GEMV; pred reads done
  }
}

extern "C" void kernel_launch(void* const* d_in, const int* in_sizes, int n_in,
                              void* d_out, int out_size, void* d_ws, size_t ws_size,
                              hipStream_t stream) {
  (void)in_sizes; (void)n_in; (void)out_size; (void)ws_size;
  Args a;
  a.initdir = (const float*)d_in[0];
  a.vel     = (const float*)d_in[1];
  a.fc_w    = (const float*)d_in[2];
  a.fc_b    = (const float*)d_in[3];
  a.W_in    = (const float*)d_in[4];
  a.W_rec   = (const float*)d_in[5];
  a.W_out   = (const float*)d_in[6];
  a.bias    = (const float*)d_in[7];
  a.out     = (float*)d_out;
  a.pbuf    = (u64*)d_ws;  // 256 WGs x 2 parity x 256 slots x 8B = 1MB

  zero_pbuf<<<256, 512, 0, stream>>>(a.pbuf);
  zero_out<<<128, 512, 0, stream>>>((float4*)d_out);  // 262144 f32

  void* args[] = { &a };
  hipLaunchCooperativeKernel((const void*)rnn_kernel, dim3(256), dim3(512),
                             args, 0, stream);
}

// Round 8
// 864.123 us; speedup vs baseline: 1.9000x; 1.4254x over previous
//
#include <hip/hip_runtime.h>
#include <math.h>

#define TT 512
#define NN 256
#define HH 512
constexpr float AL = 0.1f;

typedef unsigned int uint;
typedef unsigned long long u64;
typedef unsigned short u16;
typedef _Float16 f16;
typedef f16 f16x8 __attribute__((ext_vector_type(8)));
typedef float f32x4 __attribute__((ext_vector_type(4)));
using half2v = decltype(__builtin_amdgcn_cvt_pkrtz(0.0f, 0.0f));

struct Args {
  const float* initdir; const float* vel; const float* fc_w; const float* fc_b;
  const float* W_in; const float* W_rec; const float* W_out; const float* bias;
  float* out; uint* pbuf;
};

// Replay-safe prologues: tags must start !=1..513, out is atomicAdd-accumulated.
__global__ void zero_pbuf(u64* p) { p[blockIdx.x * 512 + threadIdx.x] = 0ull; }      // 128K u64 = 1MB
__global__ void zero_out(float4* p) { p[blockIdx.x * 512 + threadIdx.x] = float4{0,0,0,0}; }

// 256 WGs x 512 threads, cooperative. Cluster = 2 WGs (bid, bid^8) sharing 2
// batch rows; WG c owns h-cols [256c,256c+256). Exchange = ACTIVATIONS (ships
// the moment h_{t+1} exists; flight overlaps out-proj + poll). GEMV = MFMA
// 16x16x32_f16 (M=2 used of 16): weights live as B-fragments in the unified
// VGPR/AGPR file and MFMA reads them DIRECTLY -- no per-use shuttle (the r4-r7
// VALU tax). A/B k-placement uses one shared formula, so the exact HW k-order
// cancels; M/N/C-D mappings are the HW-verified ones.
__global__ __launch_bounds__(512, 1)
void rnn_kernel(Args a) {
  __shared__ alignas(16) u16 actw[2][HH];  // act_t f16 [row][global col], 2KB
  __shared__ float pred[2][256];           // y partial-free [row][own col], 2KB

  const int tid = threadIdx.x;
  const int wav = tid >> 6, lan = tid & 63;
  const int bid = blockIdx.x;
  const int kk = bid >> 3;
  const int c = kk & 1;                        // cluster rank (col slice)
  const int grp = (bid & 7) * 16 + (kk >> 1);  // n-group 0..127 (2 rows)
  const int own0 = c * 256, fo0 = (1 - c) * 256;

  // update identity: thread owns h(row g, col ucol)
  const int g = tid >> 8, jj = tid & 255;
  const int ucol = own0 + jj, ugn = grp * 2 + g;

  // GEMV identity: wave covers own cols [wav*32, wav*32+32), two 16-col tiles
  const int l15 = lan & 15, gq = lan >> 4;
  const int ncol0 = own0 + wav * 32 + l15;

  // ---- W_rec -> B-fragments (f16), k-slot (gq,j) := kb*32 + gq*8 + j.
  // Same formula builds the A-fragments below => k-mapping cancels.
  f16x8 B0[16], B1[16];
#pragma unroll
  for (int kb = 0; kb < 16; ++kb) {
#pragma unroll
    for (int j = 0; j < 8; ++j) {
      const int k = kb * 32 + gq * 8 + j;
      B0[kb][j] = (f16)a.W_rec[(size_t)k * HH + ncol0];
      B1[kb][j] = (f16)a.W_rec[(size_t)k * HH + ncol0 + 16];
    }
  }

  // update-phase parameters
  const float fw0 = a.fc_w[ucol * 2], fw1 = a.fc_w[ucol * 2 + 1], fb = a.fc_b[ucol];
  const float wi0 = AL * a.W_in[ucol], wi1 = AL * a.W_in[HH + ucol];
  const float bj = AL * a.bias[ucol];
  const float wo0 = a.W_out[ucol * 2], wo1 = a.W_out[ucol * 2 + 1];
  const float id0 = a.initdir[ugn * 2], id1 = a.initdir[ugn * 2 + 1];

  uint* shipb = a.pbuf + (size_t)(bid ^ 8) * 1024;      // peer's poll region
  const uint* pollb = a.pbuf + (size_t)bid * 1024;
  const float2* velp = (const float2*)a.vel;
  float* outf = a.out;

  float h = fmaf(id0, fw0, fmaf(id1, fw1, fb));  // h0
  {
    const float act = fmaxf(tanhf(h), 0.0f);
    const uint pk = __builtin_bit_cast(uint, __builtin_amdgcn_cvt_pkrtz(act, 0.f)) & 0xffffu;
    actw[g][ucol] = (u16)pk;                       // own half, act_0
    __hip_atomic_store(shipb + 0 * 512 + tid, (pk << 16) | 1u,
                       __ATOMIC_RELAXED, __HIP_MEMORY_SCOPE_AGENT);  // tag 1
  }

  // A-fragment row pointer: lanes 0,1 of each 16-lane group supply rows 0,1;
  // other lanes duplicate row 0 (their D-rows are ignored).
  const u16* arow = &actw[(l15 < 2) ? l15 : 0][0];

  for (int t = 0; t < TT; ++t) {
    const float2 xv = velp[t * NN + ugn];
    const int par = t & 1;

    // ---- poll foreign acts (tagged data, agent scope), fill actw foreign half
    {
      const uint want = (uint)(t + 1);
      const uint* slot = pollb + par * 512 + tid;
      uint v;
      do {
        v = __hip_atomic_load(slot, __ATOMIC_RELAXED, __HIP_MEMORY_SCOPE_AGENT);
      } while ((v & 0xffffu) != want);
      actw[g][fo0 + jj] = (u16)(v >> 16);
    }
    __syncthreads();  // B1: act_t complete in LDS

    // ---- GEMV via MFMA: D[0..1][ncol] = sum_k act[k] * W[k][ncol]
    f32x4 ac0 = {0.f, 0.f, 0.f, 0.f}, ac1 = {0.f, 0.f, 0.f, 0.f};
#pragma unroll
    for (int kb = 0; kb < 16; ++kb) {
      const f16x8 A = *(const f16x8*)(arow + kb * 32 + gq * 8);
      ac0 = __builtin_amdgcn_mfma_f32_16x16x32_f16(A, B0[kb], ac0, 0, 0, 0);
      ac1 = __builtin_amdgcn_mfma_f32_16x16x32_f16(A, B1[kb], ac1, 0, 0, 0);
    }
    if (lan < 16) {  // rows 0,1 live in lanes 0-15, regs 0,1 (verified C/D map)
      const int col = wav * 32 + l15;
      pred[0][col] = ac0[0];
      pred[1][col] = ac0[1];
      pred[0][col + 16] = ac1[0];
      pred[1][col + 16] = ac1[1];
    }
    __syncthreads();  // B2: pred ready

    // ---- leaky update; ship act_{t+1} IMMEDIATELY (flight overlaps out-proj)
    const float y = pred[g][jj];
    h = fmaf(0.9f, h, fmaf(AL, y, fmaf(xv.x, wi0, fmaf(xv.y, wi1, bj))));
    const float act = fmaxf(tanhf(h), 0.0f);
    const uint pk = __builtin_bit_cast(uint, __builtin_amdgcn_cvt_pkrtz(act, 0.f)) & 0xffffu;
    actw[g][ucol] = (u16)pk;  // own half for step t+1 (safe: post-B2)
    __hip_atomic_store(shipb + ((t + 1) & 1) * 512 + tid, (pk << 16) | (uint)(t + 2),
                       __ATOMIC_RELAXED, __HIP_MEMORY_SCOPE_AGENT);

    // ---- out[t][ugn][:] += act * W_out (wave-reduce, 2 atomicAdds/wave)
    float q0 = act * wo0, q1 = act * wo1;
#pragma unroll
    for (int off = 32; off; off >>= 1) {
      q0 += __shfl_down(q0, off);
      q1 += __shfl_down(q1, off);
    }
    if (lan == 0) {
      atomicAdd(&outf[(t * NN + ugn) * 2 + 0], q0);
      atomicAdd(&outf[(t * NN + ugn) * 2 + 1], q1);
    }
    // no 3rd barrier: next poll writes foreign actw only after B2, and the
    // next GEMV reads actw only after the next B1.
  }
}

extern "C" void kernel_launch(void* const* d_in, const int* in_sizes, int n_in,
                              void* d_out, int out_size, void* d_ws, size_t ws_size,
                              hipStream_t stream) {
  (void)in_sizes; (void)n_in; (void)out_size; (void)ws_size;
  Args a;
  a.initdir = (const float*)d_in[0];
  a.vel     = (const float*)d_in[1];
  a.fc_w    = (const float*)d_in[2];
  a.fc_b    = (const float*)d_in[3];
  a.W_in    = (const float*)d_in[4];
  a.W_rec   = (const float*)d_in[5];
  a.W_out   = (const float*)d_in[6];
  a.bias    = (const float*)d_in[7];
  a.out     = (float*)d_out;
  a.pbuf    = (uint*)d_ws;  // 256 WGs x 2 parity x 512 slots x 4B = 1MB

  zero_pbuf<<<256, 512, 0, stream>>>((u64*)a.pbuf);
  zero_out<<<128, 512, 0, stream>>>((float4*)d_out);  // 262144 f32

  void* args[] = { &a };
  hipLaunchCooperativeKernel((const void*)rnn_kernel, dim3(256), dim3(512),
                             args, 0, stream);
}